// Round 7
// baseline (231.428 us; speedup 1.0000x reference)
//
#include <hip/hip_runtime.h>
#include <hip/hip_bf16.h>
#include <cmath>

#define B     128
#define CIN   8
#define COUT  64
#define K     33
#define KP    36           // padded taps (288 = 9 * 32)
#define KKD   (KP * CIN)   // 288 reduction length, kk = tap*8 + ci
#define NSL   (KKD / 32)   // 9 MFMA K-slices
#define L     4096
#define PAD   16
#define HID   128
#define NW    3

#define TL    512          // l-tile per block
#define NROW  (TL + KP)    // 548 xT rows (pos range [l0-16, l0+TL+19])

typedef __attribute__((ext_vector_type(8))) short short8;
typedef __attribute__((ext_vector_type(4))) float f32x4;

__device__ __forceinline__ float softplusf(float v) {
    return (v > 20.f) ? v : log1pf(expf(v));
}

// ---------------------------------------------------------------------------
// Fused prologue: blocks 0..127 = agent (stats + MLP -> action),
//                 blocks 128..133 = wavelet bank build (bf16, padded layout).
// argmax(q) == argmax(a): value head & a.mean() are uniform across NW -> skip.
// Block b -> XCD b%8 (round-robin dispatch): warms L2 with x[b] for conv.
// ---------------------------------------------------------------------------
__global__ __launch_bounds__(256) void prologue_kernel(
    const float* __restrict__ x,
    const float* __restrict__ fw, const float* __restrict__ fb,
    const float* __restrict__ aw1, const float* __restrict__ ab1,
    const float* __restrict__ aw2, const float* __restrict__ ab2,
    const float* __restrict__ sp,
    int* __restrict__ actions, __hip_bfloat16* __restrict__ bankbf)
{
    const int tid = threadIdx.x;

    if (blockIdx.x < B) {
        // ---------------- agent path ----------------
        const int b = blockIdx.x;
        __shared__ float st[2 * CIN];
        __shared__ float h[HID];
        __shared__ float ha[HID];

        const int ci  = tid >> 5;
        const int sub = tid & 31;
        const float* xp = x + ((size_t)b * CIN + ci) * L;
        float s = 0.f, ss = 0.f;
        for (int j = sub; j < L / 4; j += 32) {
            float4 v = ((const float4*)xp)[j];
            s  += v.x + v.y + v.z + v.w;
            ss += v.x * v.x + v.y * v.y + v.z * v.z + v.w * v.w;
        }
        for (int m = 16; m; m >>= 1) {
            s  += __shfl_xor(s,  m);
            ss += __shfl_xor(ss, m);
        }
        if (sub == 0) {
            float mean = s / (float)L;
            float var  = fmaxf(ss - s * mean, 0.f) / (float)(L - 1);
            st[ci]       = mean;
            st[CIN + ci] = sqrtf(var);
        }
        __syncthreads();

        const int j = tid;
        if (j < HID) {
            float acc = fb[j];
            #pragma unroll
            for (int i = 0; i < 2 * CIN; ++i) acc = fmaf(st[i], fw[i * HID + j], acc);
            h[j] = fmaxf(acc, 0.f);
        }
        __syncthreads();
        if (j < HID) {
            float acc2 = ab1[j];
            for (int i = 0; i < HID; ++i) acc2 = fmaf(h[i], aw1[i * HID + j], acc2);
            ha[j] = fmaxf(acc2, 0.f);
        }
        __syncthreads();
        if (j == 0) {
            float best = -1e30f; int bi = 0;
            for (int w = 0; w < NW; ++w) {
                float a = ab2[w];
                for (int i = 0; i < HID; ++i) a = fmaf(ha[i], aw2[i * NW + w], a);
                if (a > best) { best = a; bi = w; }
            }
            actions[b] = bi;
        }
    } else {
        // ---------------- bank path ----------------
        const int t = (blockIdx.x - B) * 256 + tid;   // 6*256 = 1536 = NW*COUT*CIN
        if (t >= NW * COUT * CIN) return;
        const int nw = t >> 9;
        const int co = (t >> 3) & 63;
        const int ci = t & 7;

        const float p = sp[(co * CIN + ci) * NW + nw];
        const float scale = softplusf(p) + 1e-6f;

        float ker[K];
        float mean = 0.f;
        #pragma unroll
        for (int k = 0; k < K; ++k) {
            float g  = (float)(k - K / 2);
            float xi = g / scale;
            float v;
            if (nw == 0) {
                v = expf(-0.5f * xi * xi) * cosf(5.f * xi);
            } else if (nw == 1) {
                v = 0.8673250705840776f * (1.f - xi * xi) * expf(-0.5f * xi * xi);
            } else {
                float sgn = (g > 0.f) ? 1.f : ((g < 0.f) ? -1.f : 0.f);
                v = sgn * expf(-fabsf(xi));
            }
            ker[k] = v; mean += v;
        }
        mean *= (1.f / (float)K);
        float nrm = 0.f;
        #pragma unroll
        for (int k = 0; k < K; ++k) { ker[k] -= mean; nrm += ker[k] * ker[k]; }
        const float inv = 1.f / (sqrtf(nrm) + 1e-6f);

        __hip_bfloat16* dst = bankbf + ((size_t)(nw * COUT + co)) * KKD + ci;
        #pragma unroll
        for (int k = 0; k < K; ++k) dst[k * CIN] = __float2bfloat16(ker[k] * inv);
        #pragma unroll
        for (int k = K; k < KP; ++k) dst[k * CIN] = __float2bfloat16(0.f);
    }
}

// ---------------------------------------------------------------------------
// Conv: implicit GEMM via MFMA 16x16x32 bf16 + soft shrinkage.
//   D[l, co] = sum_kk X^T[l, kk] * W^T[kk, co],  kk = tap*8 + ci
// Operand-swapped MFMA (A = x-frag, B = w-frag) -> lane (g,ln) holds 4
// consecutive l for co = tile+ln -> f32x4 nontemporal stores.
// Flat 1024-block grid decoded so all 8 l-tiles of batch b land on
// XCD b%8 (same XCD prologue block b warmed with x[b] -> L2-hit staging).
// 8 waves: wave w -> co-pair p = w&1 (tiles 2p,2p+1), l-quarter q = w>>1.
// ---------------------------------------------------------------------------
__global__ __launch_bounds__(512, 4) void conv_kernel(
    const float* __restrict__ x, const __hip_bfloat16* __restrict__ bankbf,
    const int* __restrict__ actions, const float* __restrict__ threshold,
    float* __restrict__ out)
{
    // XCD-clustered decode: cid%8 = XCD; 16 batches per XCD; 8 l-tiles each.
    const int cid = blockIdx.x;
    const int xcd = cid & 7;
    const int j2  = cid >> 3;            // 0..127
    const int b   = xcd + 8 * (j2 & 15); // b % 8 == xcd
    const int lx  = j2 >> 4;             // 0..7
    const int l0  = lx * TL;

    const int tid  = threadIdx.x;
    const int lane = tid & 63;
    const int w    = tid >> 6;        // wave id 0..7
    const int p    = w & 1;           // co-pair: tiles 2p, 2p+1
    const int q    = w >> 1;          // l-quarter 0..3
    const int g    = lane >> 4;       // lane group 0..3 (k-chunk / l-subrow)
    const int ln   = lane & 15;

    __shared__ short8 xT[NROW];       // [pos][ci] bf16, one 16B row per pos

    // ---- stage x tile (bf16, transposed) ----
    {
        __hip_bfloat16* xb = (__hip_bfloat16*)xT;
        for (int idx = tid; idx < CIN * NROW; idx += 512) {
            int ci = idx / NROW;
            int r  = idx - ci * NROW;
            int gp = l0 - PAD + r;
            float f = (gp >= 0 && gp < L) ? x[((size_t)b * CIN + ci) * L + gp] : 0.f;
            xb[r * CIN + ci] = __float2bfloat16(f);
        }
    }

    // ---- W fragments: 2 co-tiles (32 co rows), 9 slices = 72 VGPR ----
    const int act = __builtin_amdgcn_readfirstlane(actions[b]);
    const short8* wq = (const short8*)(bankbf + (size_t)act * COUT * KKD);
    short8 aQ[2][NSL];
    #pragma unroll
    for (int cc = 0; cc < 2; ++cc) {
        const short8* wrow = wq + ((2 * p + cc) * 16 + ln) * (KKD / 8);
        #pragma unroll
        for (int s = 0; s < NSL; ++s) aQ[cc][s] = wrow[4 * s + g];
    }

    // ---- per-lane shrink threshold: co = (2p+cc)*16 + ln ----
    float tau[2];
    #pragma unroll
    for (int cc = 0; cc < 2; ++cc)
        tau[cc] = softplusf(threshold[(2 * p + cc) * 16 + ln]) + 1e-6f;

    __syncthreads();

    // ---- main loop: this wave covers local l in [q*128, q*128+128) ----
    const int wl0 = q * (TL / 4);
    #pragma unroll
    for (int lt = 0; lt < 4; ++lt) {          // 32 l per iteration
        const int lbase = wl0 + lt * 32;
        const int r0    = lbase + ln + g;     // + 4*s per slice; +16 for sub 1
        f32x4 acc[2][2] = {{{0.f,0.f,0.f,0.f},{0.f,0.f,0.f,0.f}},
                           {{0.f,0.f,0.f,0.f},{0.f,0.f,0.f,0.f}}};
        #pragma unroll
        for (int s = 0; s < NSL; ++s) {
            short8 bf0 = xT[r0 + 4 * s];
            short8 bf1 = xT[r0 + 16 + 4 * s];
            acc[0][0] = __builtin_amdgcn_mfma_f32_16x16x32_bf16(bf0, aQ[0][s], acc[0][0], 0, 0, 0);
            acc[1][0] = __builtin_amdgcn_mfma_f32_16x16x32_bf16(bf0, aQ[1][s], acc[1][0], 0, 0, 0);
            acc[0][1] = __builtin_amdgcn_mfma_f32_16x16x32_bf16(bf1, aQ[0][s], acc[0][1], 0, 0, 0);
            acc[1][1] = __builtin_amdgcn_mfma_f32_16x16x32_bf16(bf1, aQ[1][s], acc[1][1], 0, 0, 0);
        }
        // epilogue: D[l, co]; lane (g,ln): l = lbase + 16*sub + 4g + jj, co = tile + ln
        #pragma unroll
        for (int cc = 0; cc < 2; ++cc) {
            const int co = (2 * p + cc) * 16 + ln;
            float* orow = &out[((size_t)b * COUT + co) * L + l0 + lbase + 4 * g];
            #pragma unroll
            for (int sub = 0; sub < 2; ++sub) {
                f32x4 a = acc[cc][sub];
                f32x4 o;
                o[0] = copysignf(fmaxf(fabsf(a[0]) - tau[cc], 0.f), a[0]);
                o[1] = copysignf(fmaxf(fabsf(a[1]) - tau[cc], 0.f), a[1]);
                o[2] = copysignf(fmaxf(fabsf(a[2]) - tau[cc], 0.f), a[2]);
                o[3] = copysignf(fmaxf(fabsf(a[3]) - tau[cc], 0.f), a[3]);
                __builtin_nontemporal_store(o, (f32x4*)(orow + 16 * sub));
            }
        }
    }
}

// ---------------------------------------------------------------------------
extern "C" void kernel_launch(void* const* d_in, const int* in_sizes, int n_in,
                              void* d_out, int out_size, void* d_ws, size_t ws_size,
                              hipStream_t stream)
{
    const float* x           = (const float*)d_in[0];
    const float* superparams = (const float*)d_in[1];
    const float* threshold   = (const float*)d_in[2];
    const float* fw          = (const float*)d_in[3];
    const float* fb          = (const float*)d_in[4];
    // d_in[5..8] = value head (argmax-invariant, unused)
    const float* aw1         = (const float*)d_in[9];
    const float* ab1         = (const float*)d_in[10];
    const float* aw2         = (const float*)d_in[11];
    const float* ab2         = (const float*)d_in[12];
    float* out = (float*)d_out;

    int* actions            = (int*)d_ws;                            // 128 i32
    __hip_bfloat16* bankbf  = (__hip_bfloat16*)((char*)d_ws + 1024); // 3*64*288 bf16

    prologue_kernel<<<B + 6, 256, 0, stream>>>(
        x, fw, fb, aw1, ab1, aw2, ab2, superparams, actions, bankbf);
    conv_kernel<<<B * (L / TL), 512, 0, stream>>>(
        x, bankbf, actions, threshold, out);
}

// Round 8
// 197.913 us; speedup vs baseline: 1.1693x; 1.1693x over previous
//
#include <hip/hip_runtime.h>
#include <hip/hip_bf16.h>
#include <cmath>

#define B     128
#define CIN   8
#define COUT  64
#define K     33
#define KP    36           // padded taps (288 = 9 * 32)
#define KKD   (KP * CIN)   // 288 reduction length, kk = tap*8 + ci
#define NSL   (KKD / 32)   // 9 MFMA K-slices
#define L     4096
#define PAD   16
#define HID   128
#define NW    3

#define TL    1024         // l-tile per block
#define NROW  (TL + KP)    // 1060 xT rows (pos range [l0-16, l0+TL+19])
#define OSTR  40           // obuf row stride in floats (16B-aligned, bank-spread)

typedef __attribute__((ext_vector_type(8))) short short8;
typedef __attribute__((ext_vector_type(4))) float f32x4;

__device__ __forceinline__ float softplusf(float v) {
    return (v > 20.f) ? v : log1pf(expf(v));
}

// ---------------------------------------------------------------------------
// Fused prologue: blocks 0..127 = agent (stats + MLP -> action),
//                 blocks 128..133 = wavelet bank build (bf16, padded layout).
// argmax(q) == argmax(a): value head & a.mean() are uniform across NW -> skip.
// ---------------------------------------------------------------------------
__global__ __launch_bounds__(256) void prologue_kernel(
    const float* __restrict__ x,
    const float* __restrict__ fw, const float* __restrict__ fb,
    const float* __restrict__ aw1, const float* __restrict__ ab1,
    const float* __restrict__ aw2, const float* __restrict__ ab2,
    const float* __restrict__ sp,
    int* __restrict__ actions, __hip_bfloat16* __restrict__ bankbf)
{
    const int tid = threadIdx.x;

    if (blockIdx.x < B) {
        // ---------------- agent path ----------------
        const int b = blockIdx.x;
        __shared__ float st[2 * CIN];
        __shared__ float h[HID];
        __shared__ float ha[HID];

        const int ci  = tid >> 5;
        const int sub = tid & 31;
        const float* xp = x + ((size_t)b * CIN + ci) * L;
        float s = 0.f, ss = 0.f;
        for (int j = sub; j < L / 4; j += 32) {
            float4 v = ((const float4*)xp)[j];
            s  += v.x + v.y + v.z + v.w;
            ss += v.x * v.x + v.y * v.y + v.z * v.z + v.w * v.w;
        }
        for (int m = 16; m; m >>= 1) {
            s  += __shfl_xor(s,  m);
            ss += __shfl_xor(ss, m);
        }
        if (sub == 0) {
            float mean = s / (float)L;
            float var  = fmaxf(ss - s * mean, 0.f) / (float)(L - 1);
            st[ci]       = mean;
            st[CIN + ci] = sqrtf(var);
        }
        __syncthreads();

        const int j = tid;
        if (j < HID) {
            float acc = fb[j];
            #pragma unroll
            for (int i = 0; i < 2 * CIN; ++i) acc = fmaf(st[i], fw[i * HID + j], acc);
            h[j] = fmaxf(acc, 0.f);
        }
        __syncthreads();
        if (j < HID) {
            float acc2 = ab1[j];
            for (int i = 0; i < HID; ++i) acc2 = fmaf(h[i], aw1[i * HID + j], acc2);
            ha[j] = fmaxf(acc2, 0.f);
        }
        __syncthreads();
        if (j == 0) {
            float best = -1e30f; int bi = 0;
            for (int w = 0; w < NW; ++w) {
                float a = ab2[w];
                for (int i = 0; i < HID; ++i) a = fmaf(ha[i], aw2[i * NW + w], a);
                if (a > best) { best = a; bi = w; }
            }
            actions[b] = bi;
        }
    } else {
        // ---------------- bank path ----------------
        const int t = (blockIdx.x - B) * 256 + tid;   // 6*256 = 1536 = NW*COUT*CIN
        if (t >= NW * COUT * CIN) return;
        const int nw = t >> 9;
        const int co = (t >> 3) & 63;
        const int ci = t & 7;

        const float p = sp[(co * CIN + ci) * NW + nw];
        const float scale = softplusf(p) + 1e-6f;

        float ker[K];
        float mean = 0.f;
        #pragma unroll
        for (int k = 0; k < K; ++k) {
            float g  = (float)(k - K / 2);
            float xi = g / scale;
            float v;
            if (nw == 0) {
                v = expf(-0.5f * xi * xi) * cosf(5.f * xi);
            } else if (nw == 1) {
                v = 0.8673250705840776f * (1.f - xi * xi) * expf(-0.5f * xi * xi);
            } else {
                float sgn = (g > 0.f) ? 1.f : ((g < 0.f) ? -1.f : 0.f);
                v = sgn * expf(-fabsf(xi));
            }
            ker[k] = v; mean += v;
        }
        mean *= (1.f / (float)K);
        float nrm = 0.f;
        #pragma unroll
        for (int k = 0; k < K; ++k) { ker[k] -= mean; nrm += ker[k] * ker[k]; }
        const float inv = 1.f / (sqrtf(nrm) + 1e-6f);

        __hip_bfloat16* dst = bankbf + ((size_t)(nw * COUT + co)) * KKD + ci;
        #pragma unroll
        for (int k = 0; k < K; ++k) dst[k * CIN] = __float2bfloat16(ker[k] * inv);
        #pragma unroll
        for (int k = K; k < KP; ++k) dst[k * CIN] = __float2bfloat16(0.f);
    }
}

// ---------------------------------------------------------------------------
// Conv: implicit GEMM via MFMA 16x16x32 bf16 + soft shrinkage.
//   D[l, co] = sum_kk X^T[l, kk] * W^T[kk, co],  kk = tap*8 + ci
// Operand-swapped MFMA (A = x-frag, B = w-frag): lane (g,ln) holds 4
// consecutive l for co = tile+ln. Epilogue goes through a per-wave LDS
// transpose buffer so each global store instruction writes 8 co-rows x
// 128B FULL lines (fill-kernel-like write efficiency; plain stores so L2
// merges -- nt stores measured -30us in r7).
// 8 waves: wave w -> co-pair p = w&1 (tiles 2p,2p+1), l-quarter q = w>>1.
// ---------------------------------------------------------------------------
__global__ __launch_bounds__(512, 4) void conv_kernel(
    const float* __restrict__ x, const __hip_bfloat16* __restrict__ bankbf,
    const int* __restrict__ actions, const float* __restrict__ threshold,
    float* __restrict__ out)
{
    const int b  = blockIdx.y;
    const int l0 = blockIdx.x * TL;
    const int tid  = threadIdx.x;
    const int lane = tid & 63;
    const int w    = tid >> 6;        // wave id 0..7
    const int p    = w & 1;           // co-pair: tiles 2p, 2p+1
    const int q    = w >> 1;          // l-quarter 0..3 (256 l each)
    const int g    = lane >> 4;       // lane group 0..3 (k-chunk / l-subrow)
    const int ln   = lane & 15;

    __shared__ short8 xT[NROW];               // [pos][ci] bf16, 16B rows (16.96 KB)
    __shared__ float  obuf[8][32 * OSTR];     // per-wave epilogue transpose (40.96 KB)

    // ---- stage x tile (bf16, transposed), float4-vectorized ----
    {
        __hip_bfloat16* xb = (__hip_bfloat16*)xT;
        // NROW = 1060 = 4*265; vec unit = (ci, 4 consecutive r)
        for (int idx = tid; idx < CIN * (NROW / 4); idx += 512) {
            int ci = idx / (NROW / 4);
            int r4 = (idx - ci * (NROW / 4)) * 4;
            int gp = l0 - PAD + r4;
            const float* xp = x + ((size_t)b * CIN + ci) * L;
            if (gp >= 0 && gp <= L - 4) {
                float4 v = *(const float4*)&xp[gp];
                xb[(r4 + 0) * CIN + ci] = __float2bfloat16(v.x);
                xb[(r4 + 1) * CIN + ci] = __float2bfloat16(v.y);
                xb[(r4 + 2) * CIN + ci] = __float2bfloat16(v.z);
                xb[(r4 + 3) * CIN + ci] = __float2bfloat16(v.w);
            } else {
                #pragma unroll
                for (int e = 0; e < 4; ++e) {
                    int gpe = gp + e;
                    float f = (gpe >= 0 && gpe < L) ? xp[gpe] : 0.f;
                    xb[(r4 + e) * CIN + ci] = __float2bfloat16(f);
                }
            }
        }
    }

    // ---- W fragments: 2 co-tiles (32 co rows), 9 slices = 72 VGPR ----
    const int act = __builtin_amdgcn_readfirstlane(actions[b]);
    const short8* wq = (const short8*)(bankbf + (size_t)act * COUT * KKD);
    short8 aQ[2][NSL];
    #pragma unroll
    for (int cc = 0; cc < 2; ++cc) {
        const short8* wrow = wq + ((2 * p + cc) * 16 + ln) * (KKD / 8);
        #pragma unroll
        for (int s = 0; s < NSL; ++s) aQ[cc][s] = wrow[4 * s + g];
    }

    // ---- per-lane shrink threshold: co = (2p+cc)*16 + ln ----
    float tau[2];
    #pragma unroll
    for (int cc = 0; cc < 2; ++cc)
        tau[cc] = softplusf(threshold[(2 * p + cc) * 16 + ln]) + 1e-6f;

    // store-phase lane remap: lane = co_r*8 + lc
    const int co_r = lane >> 3;   // 0..7
    const int lc   = lane & 7;    // 0..7 (16B l-chunk)

    __syncthreads();

    // ---- main loop: this wave covers local l in [q*256, q*256+256) ----
    const int wl0 = q * (TL / 4);
    for (int lt = 0; lt < (TL / 4) / 32; ++lt) {   // 8 iters of 32 l
        const int lbase = wl0 + lt * 32;
        const int r0    = lbase + ln + g;          // + 4*s per slice; +16 for sub 1
        f32x4 acc[2][2] = {{{0.f,0.f,0.f,0.f},{0.f,0.f,0.f,0.f}},
                           {{0.f,0.f,0.f,0.f},{0.f,0.f,0.f,0.f}}};
        #pragma unroll
        for (int s = 0; s < NSL; ++s) {
            short8 bf0 = xT[r0 + 4 * s];
            short8 bf1 = xT[r0 + 16 + 4 * s];
            acc[0][0] = __builtin_amdgcn_mfma_f32_16x16x32_bf16(bf0, aQ[0][s], acc[0][0], 0, 0, 0);
            acc[1][0] = __builtin_amdgcn_mfma_f32_16x16x32_bf16(bf0, aQ[1][s], acc[1][0], 0, 0, 0);
            acc[0][1] = __builtin_amdgcn_mfma_f32_16x16x32_bf16(bf1, aQ[0][s], acc[0][1], 0, 0, 0);
            acc[1][1] = __builtin_amdgcn_mfma_f32_16x16x32_bf16(bf1, aQ[1][s], acc[1][1], 0, 0, 0);
        }

        // ---- epilogue stage 1: shrink + LDS transpose buffer ----
        // lane (g,ln) result: co_local = cc*16+ln, l_local = 16*sub + 4*g + j
        #pragma unroll
        for (int cc = 0; cc < 2; ++cc) {
            #pragma unroll
            for (int sub = 0; sub < 2; ++sub) {
                f32x4 a = acc[cc][sub];
                f32x4 o;
                o[0] = copysignf(fmaxf(fabsf(a[0]) - tau[cc], 0.f), a[0]);
                o[1] = copysignf(fmaxf(fabsf(a[1]) - tau[cc], 0.f), a[1]);
                o[2] = copysignf(fmaxf(fabsf(a[2]) - tau[cc], 0.f), a[2]);
                o[3] = copysignf(fmaxf(fabsf(a[3]) - tau[cc], 0.f), a[3]);
                *(f32x4*)&obuf[w][(cc * 16 + ln) * OSTR + 16 * sub + 4 * g] = o;
            }
        }

        // ---- epilogue stage 2: read back lane-remapped, full-line stores ----
        // instruction i: 8 co-rows (co_local = co_r + 8i) x 128B contiguous l
        #pragma unroll
        for (int i = 0; i < 4; ++i) {
            const int col = co_r + 8 * i;                       // 0..31
            f32x4 v = *(const f32x4*)&obuf[w][col * OSTR + 4 * lc];
            const int co = (2 * p + (col >> 4)) * 16 + (col & 15);
            *(f32x4*)&out[((size_t)b * COUT + co) * L + l0 + lbase + 4 * lc] = v;
        }
    }
}

// ---------------------------------------------------------------------------
extern "C" void kernel_launch(void* const* d_in, const int* in_sizes, int n_in,
                              void* d_out, int out_size, void* d_ws, size_t ws_size,
                              hipStream_t stream)
{
    const float* x           = (const float*)d_in[0];
    const float* superparams = (const float*)d_in[1];
    const float* threshold   = (const float*)d_in[2];
    const float* fw          = (const float*)d_in[3];
    const float* fb          = (const float*)d_in[4];
    // d_in[5..8] = value head (argmax-invariant, unused)
    const float* aw1         = (const float*)d_in[9];
    const float* ab1         = (const float*)d_in[10];
    const float* aw2         = (const float*)d_in[11];
    const float* ab2         = (const float*)d_in[12];
    float* out = (float*)d_out;

    int* actions            = (int*)d_ws;                            // 128 i32
    __hip_bfloat16* bankbf  = (__hip_bfloat16*)((char*)d_ws + 1024); // 3*64*288 bf16

    prologue_kernel<<<B + 6, 256, 0, stream>>>(
        x, fw, fb, aw1, ab1, aw2, ab2, superparams, actions, bankbf);
    conv_kernel<<<dim3(L / TL, B), 512, 0, stream>>>(
        x, bankbf, actions, threshold, out);
}

// Round 9
// 192.847 us; speedup vs baseline: 1.2001x; 1.0263x over previous
//
#include <hip/hip_runtime.h>
#include <hip/hip_bf16.h>
#include <cmath>

#define B     128
#define CIN   8
#define COUT  64
#define K     33
#define KP    36           // padded taps (288 = 9 * 32)
#define KKD   (KP * CIN)   // 288 reduction length, kk = tap*8 + ci
#define NSL   (KKD / 32)   // 9 MFMA K-slices
#define L     4096
#define PAD   16
#define HID   128
#define NW    3

#define TL    1024         // l-tile per block
#define NROW  (TL + KP)    // 1060 xT rows
#define OSTR  40           // obuf row stride in floats
#define XROWS (PAD + L + KP)   // 4148 rows per batch in padded bf16 copy

typedef __attribute__((ext_vector_type(8))) short short8;
typedef __attribute__((ext_vector_type(4))) float f32x4;

__device__ __forceinline__ float softplusf(float v) {
    return (v > 20.f) ? v : log1pf(expf(v));
}
__device__ __forceinline__ short f2bf(float f) {
    __hip_bfloat16 h = __float2bfloat16(f);
    return *reinterpret_cast<short*>(&h);
}

// ---------------------------------------------------------------------------
// Path A kernel 1: full-grid stats partials + padded bf16 transpose of x.
// Grid B*8: block (b, ls) handles l in [ls*512, ls*512+512).
// ---------------------------------------------------------------------------
__global__ __launch_bounds__(256) void statcast_kernel(
    const float* __restrict__ x, __hip_bfloat16* __restrict__ xg,
    float* __restrict__ psum)          // [2][B*8ls*8ci]
{
    const int bid = blockIdx.x;
    const int b  = bid >> 3;
    const int ls = bid & 7;
    const int tid  = threadIdx.x;
    const int lane = tid & 63;
    const int wv   = tid >> 6;
    const int l    = ls * 512 + 2 * tid;   // 2 consecutive l per thread

    float2 v[CIN];
    float s[CIN], q[CIN];
    #pragma unroll
    for (int ci = 0; ci < CIN; ++ci) {
        v[ci] = *(const float2*)&x[((size_t)b * CIN + ci) * L + l];
        s[ci] = v[ci].x + v[ci].y;
        q[ci] = v[ci].x * v[ci].x + v[ci].y * v[ci].y;
    }

    // transposed bf16 rows (32B contiguous per thread)
    short8 ra, rb;
    #pragma unroll
    for (int ci = 0; ci < CIN; ++ci) {
        ra[ci] = f2bf(v[ci].x);
        rb[ci] = f2bf(v[ci].y);
    }
    short8* xr = (short8*)xg + (size_t)b * XROWS + PAD + l;
    xr[0] = ra;
    xr[1] = rb;

    // zero the pad rows
    short8 z8 = {0,0,0,0,0,0,0,0};
    if (ls == 0 && tid < PAD) ((short8*)xg)[(size_t)b * XROWS + tid] = z8;
    if (ls == 7 && tid < KP)  ((short8*)xg)[(size_t)b * XROWS + PAD + L + tid] = z8;

    // wave reduce then block reduce
    #pragma unroll
    for (int m = 32; m; m >>= 1) {
        #pragma unroll
        for (int ci = 0; ci < CIN; ++ci) {
            s[ci] += __shfl_xor(s[ci], m);
            q[ci] += __shfl_xor(q[ci], m);
        }
    }
    __shared__ float rs[4][CIN], rq[4][CIN];
    if (lane == 0) {
        #pragma unroll
        for (int ci = 0; ci < CIN; ++ci) { rs[wv][ci] = s[ci]; rq[wv][ci] = q[ci]; }
    }
    __syncthreads();
    if (tid < CIN) {
        float S = rs[0][tid] + rs[1][tid] + rs[2][tid] + rs[3][tid];
        float Q = rq[0][tid] + rq[1][tid] + rq[2][tid] + rq[3][tid];
        psum[bid * CIN + tid]             = S;
        psum[B * 64 + bid * CIN + tid]    = Q;
    }
}

// ---------------------------------------------------------------------------
// Path A kernel 2: blocks 0..127 reduce psums -> MLP -> action;
//                  blocks 128..133 build wavelet bank.
// argmax(q) == argmax(a): value head & a.mean() uniform across NW -> skip.
// ---------------------------------------------------------------------------
__global__ __launch_bounds__(256) void mlpbank_kernel(
    const float* __restrict__ psum,
    const float* __restrict__ fw, const float* __restrict__ fb,
    const float* __restrict__ aw1, const float* __restrict__ ab1,
    const float* __restrict__ aw2, const float* __restrict__ ab2,
    const float* __restrict__ sp,
    int* __restrict__ actions, __hip_bfloat16* __restrict__ bankbf)
{
    const int tid = threadIdx.x;

    if (blockIdx.x < B) {
        const int b = blockIdx.x;
        __shared__ float st[2 * CIN];
        __shared__ float h[HID];
        __shared__ float ha[HID];

        if (tid < CIN) {
            float S = 0.f, Q = 0.f;
            #pragma unroll
            for (int ls = 0; ls < 8; ++ls) {
                S += psum[(b * 8 + ls) * CIN + tid];
                Q += psum[B * 64 + (b * 8 + ls) * CIN + tid];
            }
            float mean = S / (float)L;
            float var  = fmaxf(Q - S * mean, 0.f) / (float)(L - 1);
            st[tid]       = mean;
            st[CIN + tid] = sqrtf(var);
        }
        __syncthreads();

        if (tid < HID) {
            float acc = fb[tid];
            #pragma unroll
            for (int i = 0; i < 2 * CIN; ++i) acc = fmaf(st[i], fw[i * HID + tid], acc);
            h[tid] = fmaxf(acc, 0.f);
        }
        __syncthreads();
        if (tid < HID) {
            float acc2 = ab1[tid];
            for (int i = 0; i < HID; ++i) acc2 = fmaf(h[i], aw1[i * HID + tid], acc2);
            ha[tid] = fmaxf(acc2, 0.f);
        }
        __syncthreads();
        if (tid == 0) {
            float best = -1e30f; int bi = 0;
            for (int w = 0; w < NW; ++w) {
                float a = ab2[w];
                for (int i = 0; i < HID; ++i) a = fmaf(ha[i], aw2[i * NW + w], a);
                if (a > best) { best = a; bi = w; }
            }
            actions[b] = bi;
        }
    } else {
        const int t = (blockIdx.x - B) * 256 + tid;   // 1536 = NW*COUT*CIN
        if (t >= NW * COUT * CIN) return;
        const int nw = t >> 9;
        const int co = (t >> 3) & 63;
        const int ci = t & 7;

        const float p = sp[(co * CIN + ci) * NW + nw];
        const float scale = softplusf(p) + 1e-6f;

        float ker[K];
        float mean = 0.f;
        #pragma unroll
        for (int k = 0; k < K; ++k) {
            float g  = (float)(k - K / 2);
            float xi = g / scale;
            float vv;
            if (nw == 0) {
                vv = expf(-0.5f * xi * xi) * cosf(5.f * xi);
            } else if (nw == 1) {
                vv = 0.8673250705840776f * (1.f - xi * xi) * expf(-0.5f * xi * xi);
            } else {
                float sgn = (g > 0.f) ? 1.f : ((g < 0.f) ? -1.f : 0.f);
                vv = sgn * expf(-fabsf(xi));
            }
            ker[k] = vv; mean += vv;
        }
        mean *= (1.f / (float)K);
        float nrm = 0.f;
        #pragma unroll
        for (int k = 0; k < K; ++k) { ker[k] -= mean; nrm += ker[k] * ker[k]; }
        const float inv = 1.f / (sqrtf(nrm) + 1e-6f);

        __hip_bfloat16* dst = bankbf + ((size_t)(nw * COUT + co)) * KKD + ci;
        #pragma unroll
        for (int k = 0; k < K; ++k) dst[k * CIN] = __float2bfloat16(ker[k] * inv);
        #pragma unroll
        for (int k = K; k < KP; ++k) dst[k * CIN] = __float2bfloat16(0.f);
    }
}

// ---------------------------------------------------------------------------
// Path B prologue (r8 fallback, unchanged): agent + bank in one kernel.
// ---------------------------------------------------------------------------
__global__ __launch_bounds__(256) void prologue_kernel(
    const float* __restrict__ x,
    const float* __restrict__ fw, const float* __restrict__ fb,
    const float* __restrict__ aw1, const float* __restrict__ ab1,
    const float* __restrict__ aw2, const float* __restrict__ ab2,
    const float* __restrict__ sp,
    int* __restrict__ actions, __hip_bfloat16* __restrict__ bankbf)
{
    const int tid = threadIdx.x;

    if (blockIdx.x < B) {
        const int b = blockIdx.x;
        __shared__ float st[2 * CIN];
        __shared__ float h[HID];
        __shared__ float ha[HID];

        const int ci  = tid >> 5;
        const int sub = tid & 31;
        const float* xp = x + ((size_t)b * CIN + ci) * L;
        float s = 0.f, ss = 0.f;
        for (int j = sub; j < L / 4; j += 32) {
            float4 v = ((const float4*)xp)[j];
            s  += v.x + v.y + v.z + v.w;
            ss += v.x * v.x + v.y * v.y + v.z * v.z + v.w * v.w;
        }
        for (int m = 16; m; m >>= 1) {
            s  += __shfl_xor(s,  m);
            ss += __shfl_xor(ss, m);
        }
        if (sub == 0) {
            float mean = s / (float)L;
            float var  = fmaxf(ss - s * mean, 0.f) / (float)(L - 1);
            st[ci]       = mean;
            st[CIN + ci] = sqrtf(var);
        }
        __syncthreads();

        if (tid < HID) {
            float acc = fb[tid];
            #pragma unroll
            for (int i = 0; i < 2 * CIN; ++i) acc = fmaf(st[i], fw[i * HID + tid], acc);
            h[tid] = fmaxf(acc, 0.f);
        }
        __syncthreads();
        if (tid < HID) {
            float acc2 = ab1[tid];
            for (int i = 0; i < HID; ++i) acc2 = fmaf(h[i], aw1[i * HID + tid], acc2);
            ha[tid] = fmaxf(acc2, 0.f);
        }
        __syncthreads();
        if (tid == 0) {
            float best = -1e30f; int bi = 0;
            for (int w = 0; w < NW; ++w) {
                float a = ab2[w];
                for (int i = 0; i < HID; ++i) a = fmaf(ha[i], aw2[i * NW + w], a);
                if (a > best) { best = a; bi = w; }
            }
            actions[b] = bi;
        }
    } else {
        const int t = (blockIdx.x - B) * 256 + tid;
        if (t >= NW * COUT * CIN) return;
        const int nw = t >> 9;
        const int co = (t >> 3) & 63;
        const int ci = t & 7;

        const float p = sp[(co * CIN + ci) * NW + nw];
        const float scale = softplusf(p) + 1e-6f;

        float ker[K];
        float mean = 0.f;
        #pragma unroll
        for (int k = 0; k < K; ++k) {
            float g  = (float)(k - K / 2);
            float xi = g / scale;
            float vv;
            if (nw == 0) {
                vv = expf(-0.5f * xi * xi) * cosf(5.f * xi);
            } else if (nw == 1) {
                vv = 0.8673250705840776f * (1.f - xi * xi) * expf(-0.5f * xi * xi);
            } else {
                float sgn = (g > 0.f) ? 1.f : ((g < 0.f) ? -1.f : 0.f);
                vv = sgn * expf(-fabsf(xi));
            }
            ker[k] = vv; mean += vv;
        }
        mean *= (1.f / (float)K);
        float nrm = 0.f;
        #pragma unroll
        for (int k = 0; k < K; ++k) { ker[k] -= mean; nrm += ker[k] * ker[k]; }
        const float inv = 1.f / (sqrtf(nrm) + 1e-6f);

        __hip_bfloat16* dst = bankbf + ((size_t)(nw * COUT + co)) * KKD + ci;
        #pragma unroll
        for (int k = 0; k < K; ++k) dst[k * CIN] = __float2bfloat16(ker[k] * inv);
        #pragma unroll
        for (int k = K; k < KP; ++k) dst[k * CIN] = __float2bfloat16(0.f);
    }
}

// ---------------------------------------------------------------------------
// Conv: implicit GEMM via MFMA 16x16x32 bf16 + soft shrinkage.
// XGPATH=1: stage LDS by straight short8 copy from the padded bf16 copy.
// XGPATH=0: r8 behavior (fp32 load + convert).
// Epilogue via per-wave LDS transpose -> full 128B-line stores.
// ---------------------------------------------------------------------------
template<int XGPATH>
__global__ __launch_bounds__(512, 4) void conv_kernel(
    const float* __restrict__ x, const __hip_bfloat16* __restrict__ xg,
    const __hip_bfloat16* __restrict__ bankbf,
    const int* __restrict__ actions, const float* __restrict__ threshold,
    float* __restrict__ out)
{
    const int b  = blockIdx.y;
    const int l0 = blockIdx.x * TL;
    const int tid  = threadIdx.x;
    const int lane = tid & 63;
    const int w    = tid >> 6;
    const int p    = w & 1;
    const int q    = w >> 1;
    const int g    = lane >> 4;
    const int ln   = lane & 15;

    __shared__ short8 xT[NROW];
    __shared__ float  obuf[8][32 * OSTR];

    if constexpr (XGPATH) {
        const short8* xr = (const short8*)xg + (size_t)b * XROWS + l0;
        for (int r = tid; r < NROW; r += 512) xT[r] = xr[r];
    } else {
        __hip_bfloat16* xb = (__hip_bfloat16*)xT;
        for (int idx = tid; idx < CIN * (NROW / 4); idx += 512) {
            int ci = idx / (NROW / 4);
            int r4 = (idx - ci * (NROW / 4)) * 4;
            int gp = l0 - PAD + r4;
            const float* xp = x + ((size_t)b * CIN + ci) * L;
            if (gp >= 0 && gp <= L - 4) {
                float4 v = *(const float4*)&xp[gp];
                xb[(r4 + 0) * CIN + ci] = __float2bfloat16(v.x);
                xb[(r4 + 1) * CIN + ci] = __float2bfloat16(v.y);
                xb[(r4 + 2) * CIN + ci] = __float2bfloat16(v.z);
                xb[(r4 + 3) * CIN + ci] = __float2bfloat16(v.w);
            } else {
                #pragma unroll
                for (int e = 0; e < 4; ++e) {
                    int gpe = gp + e;
                    float f = (gpe >= 0 && gpe < L) ? xp[gpe] : 0.f;
                    xb[(r4 + e) * CIN + ci] = __float2bfloat16(f);
                }
            }
        }
    }

    const int act = __builtin_amdgcn_readfirstlane(actions[b]);
    const short8* wq = (const short8*)(bankbf + (size_t)act * COUT * KKD);
    short8 aQ[2][NSL];
    #pragma unroll
    for (int cc = 0; cc < 2; ++cc) {
        const short8* wrow = wq + ((2 * p + cc) * 16 + ln) * (KKD / 8);
        #pragma unroll
        for (int s = 0; s < NSL; ++s) aQ[cc][s] = wrow[4 * s + g];
    }

    float tau[2];
    #pragma unroll
    for (int cc = 0; cc < 2; ++cc)
        tau[cc] = softplusf(threshold[(2 * p + cc) * 16 + ln]) + 1e-6f;

    const int co_r = lane >> 3;
    const int lc   = lane & 7;

    __syncthreads();

    const int wl0 = q * (TL / 4);
    for (int lt = 0; lt < (TL / 4) / 32; ++lt) {
        const int lbase = wl0 + lt * 32;
        const int r0    = lbase + ln + g;
        f32x4 acc[2][2] = {{{0.f,0.f,0.f,0.f},{0.f,0.f,0.f,0.f}},
                           {{0.f,0.f,0.f,0.f},{0.f,0.f,0.f,0.f}}};
        #pragma unroll
        for (int s = 0; s < NSL; ++s) {
            short8 bf0 = xT[r0 + 4 * s];
            short8 bf1 = xT[r0 + 16 + 4 * s];
            acc[0][0] = __builtin_amdgcn_mfma_f32_16x16x32_bf16(bf0, aQ[0][s], acc[0][0], 0, 0, 0);
            acc[1][0] = __builtin_amdgcn_mfma_f32_16x16x32_bf16(bf0, aQ[1][s], acc[1][0], 0, 0, 0);
            acc[0][1] = __builtin_amdgcn_mfma_f32_16x16x32_bf16(bf1, aQ[0][s], acc[0][1], 0, 0, 0);
            acc[1][1] = __builtin_amdgcn_mfma_f32_16x16x32_bf16(bf1, aQ[1][s], acc[1][1], 0, 0, 0);
        }

        #pragma unroll
        for (int cc = 0; cc < 2; ++cc) {
            #pragma unroll
            for (int sub = 0; sub < 2; ++sub) {
                f32x4 a = acc[cc][sub];
                f32x4 o;
                o[0] = copysignf(fmaxf(fabsf(a[0]) - tau[cc], 0.f), a[0]);
                o[1] = copysignf(fmaxf(fabsf(a[1]) - tau[cc], 0.f), a[1]);
                o[2] = copysignf(fmaxf(fabsf(a[2]) - tau[cc], 0.f), a[2]);
                o[3] = copysignf(fmaxf(fabsf(a[3]) - tau[cc], 0.f), a[3]);
                *(f32x4*)&obuf[w][(cc * 16 + ln) * OSTR + 16 * sub + 4 * g] = o;
            }
        }

        #pragma unroll
        for (int i = 0; i < 4; ++i) {
            const int col = co_r + 8 * i;
            f32x4 v = *(const f32x4*)&obuf[w][col * OSTR + 4 * lc];
            const int co = (2 * p + (col >> 4)) * 16 + (col & 15);
            *(f32x4*)&out[((size_t)b * COUT + co) * L + l0 + lbase + 4 * lc] = v;
        }
    }
}

// ---------------------------------------------------------------------------
extern "C" void kernel_launch(void* const* d_in, const int* in_sizes, int n_in,
                              void* d_out, int out_size, void* d_ws, size_t ws_size,
                              hipStream_t stream)
{
    const float* x           = (const float*)d_in[0];
    const float* superparams = (const float*)d_in[1];
    const float* threshold   = (const float*)d_in[2];
    const float* fw          = (const float*)d_in[3];
    const float* fb          = (const float*)d_in[4];
    // d_in[5..8] = value head (argmax-invariant, unused)
    const float* aw1         = (const float*)d_in[9];
    const float* ab1         = (const float*)d_in[10];
    const float* aw2         = (const float*)d_in[11];
    const float* ab2         = (const float*)d_in[12];
    float* out = (float*)d_out;

    // workspace layout
    int*            actions = (int*)d_ws;                                  // 512 B
    float*          psum    = (float*)((char*)d_ws + 4096);                // 64 KB
    __hip_bfloat16* bankbf  = (__hip_bfloat16*)((char*)d_ws + 81920);      // 108 KB
    __hip_bfloat16* xg      = (__hip_bfloat16*)((char*)d_ws + 262144);     // 8.5 MB
    const size_t needed = 262144 + (size_t)B * XROWS * CIN * 2;

    if (ws_size >= needed) {
        statcast_kernel<<<B * 8, 256, 0, stream>>>(x, xg, psum);
        mlpbank_kernel<<<B + 6, 256, 0, stream>>>(
            psum, fw, fb, aw1, ab1, aw2, ab2, superparams, actions, bankbf);
        conv_kernel<1><<<dim3(L / TL, B), 512, 0, stream>>>(
            x, xg, bankbf, actions, threshold, out);
    } else {
        prologue_kernel<<<B + 6, 256, 0, stream>>>(
            x, fw, fb, aw1, ab1, aw2, ab2, superparams, actions, bankbf);
        conv_kernel<0><<<dim3(L / TL, B), 512, 0, stream>>>(
            x, xg, bankbf, actions, threshold, out);
    }
}